// Round 3
// baseline (347.558 us; speedup 1.0000x reference)
//
#include <hip/hip_runtime.h>
#include <cstdint>

// MoE: B=16384 rows, D=2048 feat, E=16 experts, C=64 classes/expert.
// R6: fp32 vector GEMM capped at ~53 TF (R3/R5: VALUBusy ~45%, occupancy
// lever was a no-op). Switch both GEMMs to f16x3 MFMA emulation of fp32
// (a = hi + lo*2^-11, lo stored pre-scaled by 2048 so it stays f16-normal;
// two accumulators: accH = hi*hi, accC = hi*lo' + lo'*hi; y = accH +
// accC/2048). Error ~1e-6 abs == current fp32 reorder noise. MFMA
// 16x16x32_f16 @ ~2.5PF/3 = ~830 TF effective vs 157 TF fp32 VALU roof.
// Pipeline: convert_w (w->f16 h/l) ; coarse_fused (feat f32 read ONCE ->
// featH/L write + full-K MFMA coarse + bias/argmax/eid/rowList fused, no
// LDS operands, no K-loop barriers) ; expert_gemm (MFMA, A-frags direct
// from L3-resident featH/L, B-frags from L2-hot ewH/L, SK=8) ; finish_rows.
// Fragment layout (m91/m97-verified convention): A/B frag = 8 contiguous
// k at row/col (lane&15), k-base (lane>>4)*8; C/D col=lane&15,
// row=(lane>>4)*4+reg.
typedef _Float16 f16;
typedef f16 f16x8 __attribute__((ext_vector_type(8)));
typedef float f32x4 __attribute__((ext_vector_type(4)));
#define MFMA16(a, b, c) __builtin_amdgcn_mfma_f32_16x16x32_f16((a), (b), (c), 0, 0, 0)

static constexpr int B_ = 16384;
static constexpr int D_ = 2048;
static constexpr int E_ = 16;
static constexpr int C_ = 64;
static constexpr float LSC = 2048.0f;     // lo-term scale (2^11)
static constexpr float ILSC = 1.0f / 2048.0f;
static constexpr int TR_E = 128;          // expert tile rows
static constexpr int SK_E = 8;            // expert split-K
static constexpr int MAXITEMS = (B_ / TR_E) + E_;  // 144 worst case

// ---- one-shot weight conversion: w -> (hi f16, lo f16 scaled by 2048) ----
__global__ __launch_bounds__(256) void convert_w(
    const float* __restrict__ cw, const float* __restrict__ ew,
    f16* __restrict__ cwH, f16* __restrict__ cwL,
    f16* __restrict__ ewH, f16* __restrict__ ewL) {
  const int g = blockIdx.x;
  const int tid = threadIdx.x;
  const float* src;
  f16 *dh, *dl;
  size_t off;
  if (g < 16) {  // cw: 16*2048 = 32768 elems = 16 blocks * 256 * 8
    off = ((size_t)g * 256 + tid) * 8;
    src = cw; dh = cwH; dl = cwL;
  } else {       // ew: 16*64*2048 = 2097152 elems = 1024 blocks * 256 * 8
    off = ((size_t)(g - 16) * 256 + tid) * 8;
    src = ew; dh = ewH; dl = ewL;
  }
  const float4 v0 = *(const float4*)(src + off);
  const float4 v1 = *(const float4*)(src + off + 4);
  const float av[8] = {v0.x, v0.y, v0.z, v0.w, v1.x, v1.y, v1.z, v1.w};
  f16x8 h8, l8;
#pragma unroll
  for (int j = 0; j < 8; ++j) {
    const f16 hh = (f16)av[j];
    h8[j] = hh;
    l8[j] = (f16)((av[j] - (float)hh) * LSC);
  }
  *(f16x8*)(dh + off) = h8;
  *(f16x8*)(dl + off) = l8;
}

// ---- fused: feat f32 -> featH/L + full-K MFMA coarse + argmax + routing ----
// 256 blocks x 512 thr. Block owns 64 rows; wave w: strip (w&3) of 16 rows,
// K-half (w>>2) of 1024. No LDS operands; A-frags are the freshly converted
// registers, B-frags direct global from L2-hot cwH/L (128 KB).
__global__ __launch_bounds__(512) void coarse_fused(
    const float* __restrict__ feat, const f16* __restrict__ cwH,
    const f16* __restrict__ cwL, const float* __restrict__ cb,
    f16* __restrict__ featH, f16* __restrict__ featL,
    float* __restrict__ out0, float* __restrict__ out1,
    int* __restrict__ eidArr, int* __restrict__ cnt,
    int* __restrict__ rowList) {
  __shared__ float red[4 * 16 * 16];  // [strip][row16][e16] from K-half 1
  __shared__ int lcnt[E_];
  __shared__ int lbase[E_];
  const int tid = threadIdx.x;
  const int lane = tid & 63;
  const int w = tid >> 6;
  const int strip = w & 3;
  const int khalf = w >> 2;
  const int rl = lane & 15;   // A row / B col (expert) index
  const int kq = lane >> 4;   // k-quad
  if (tid < E_) lcnt[tid] = 0;

  const int row = blockIdx.x * 64 + strip * 16 + rl;
  const int k00 = khalf * (D_ / 2);  // 32 chunks of 32 each

  const float* fr = feat + (size_t)row * D_ + k00 + kq * 8;
  f16* pH = featH + (size_t)row * D_ + k00 + kq * 8;
  f16* pL = featL + (size_t)row * D_ + k00 + kq * 8;
  const f16* bhp = cwH + (size_t)rl * D_ + k00 + kq * 8;
  const f16* blp = cwL + (size_t)rl * D_ + k00 + kq * 8;

  f32x4 aH = {0.f, 0.f, 0.f, 0.f};
  f32x4 aC = {0.f, 0.f, 0.f, 0.f};

  float4 v0 = *(const float4*)(fr);
  float4 v1 = *(const float4*)(fr + 4);
  for (int ch = 0; ch < 32; ++ch) {
    const float av[8] = {v0.x, v0.y, v0.z, v0.w, v1.x, v1.y, v1.z, v1.w};
    if (ch + 1 < 32) {  // prefetch next chunk's A
      v0 = *(const float4*)(fr + (ch + 1) * 32);
      v1 = *(const float4*)(fr + (ch + 1) * 32 + 4);
    }
    f16x8 h8, l8;
#pragma unroll
    for (int j = 0; j < 8; ++j) {
      const f16 hh = (f16)av[j];
      h8[j] = hh;
      l8[j] = (f16)((av[j] - (float)hh) * LSC);
    }
    *(f16x8*)(pH + ch * 32) = h8;
    *(f16x8*)(pL + ch * 32) = l8;
    const f16x8 bh = *(const f16x8*)(bhp + ch * 32);
    const f16x8 bl = *(const f16x8*)(blp + ch * 32);
    aH = MFMA16(h8, bh, aH);
    aC = MFMA16(h8, bl, aC);
    aC = MFMA16(l8, bh, aC);
  }

  if (w >= 4) {  // K-half 1: deposit merged partial for waves 0-3
#pragma unroll
    for (int reg = 0; reg < 4; ++reg)
      red[strip * 256 + (kq * 4 + reg) * 16 + rl] = aH[reg] + aC[reg] * ILSC;
  }
  __syncthreads();

  int best[4], lpos[4], grow[4];
  if (w < 4) {
    const float bias = cb[rl];
    float val[4];
#pragma unroll
    for (int reg = 0; reg < 4; ++reg) {
      grow[reg] = blockIdx.x * 64 + strip * 16 + kq * 4 + reg;
      val[reg] = aH[reg] + aC[reg] * ILSC +
                 red[strip * 256 + (kq * 4 + reg) * 16 + rl] + bias;
      out0[(size_t)grow[reg] * E_ + rl] = val[reg];
    }
    // argmax over experts (16-lane group), first-occurrence tie-break
#pragma unroll
    for (int reg = 0; reg < 4; ++reg) {
      float av2 = val[reg];
      int ai = rl;
#pragma unroll
      for (int off = 8; off; off >>= 1) {
        const float ov = __shfl_xor(av2, off, 16);
        const int oi = __shfl_xor(ai, off, 16);
        if (ov > av2 || (ov == av2 && oi < ai)) { av2 = ov; ai = oi; }
      }
      best[reg] = ai;
    }
    if (rl == 0) {
#pragma unroll
      for (int reg = 0; reg < 4; ++reg) {
        out1[grow[reg]] = (float)best[reg];
        eidArr[grow[reg]] = best[reg];
        lpos[reg] = atomicAdd(&lcnt[best[reg]], 1);
      }
    }
  }
  __syncthreads();
  if (tid < E_) lbase[tid] = atomicAdd(&cnt[tid], lcnt[tid]);
  __syncthreads();
  if (w < 4 && rl == 0) {
#pragma unroll
    for (int reg = 0; reg < 4; ++reg)
      rowList[best[reg] * B_ + lbase[best[reg]] + lpos[reg]] = grow[reg];
  }
}

// ---- dense (e, tile) worker list for the expert GEMM ----
__global__ void make_schedule(const int* __restrict__ cnt,
                              int* __restrict__ sched,
                              int* __restrict__ nItems) {
  __shared__ int tiles[E_];
  __shared__ int offs[E_];
  const int t = threadIdx.x;
  if (t < E_) tiles[t] = (cnt[t] + TR_E - 1) / TR_E;
  __syncthreads();
  if (t == 0) {
    int acc = 0;
    for (int e = 0; e < E_; ++e) { offs[e] = acc; acc += tiles[e]; }
    *nItems = acc;
  }
  __syncthreads();
  if (t < E_) {
    const int o = offs[t], n = tiles[t];
    for (int k = 0; k < n; ++k) sched[o + k] = t | (k << 8);
  }
}

// ---- expert GEMM: f16x3 MFMA, no LDS operands ----
// Tile 128 rows x 64 cols, 4 waves (wave = 2 strips x 16 rows x 64 cols),
// split-K 8 (K-range 256 = 8 chunks of 32). A-frags gathered direct from
// featH/L (L3-resident), B-frags from ewH/L (L2-hot).
__global__ __launch_bounds__(256) void expert_gemm(
    const f16* __restrict__ featH, const f16* __restrict__ featL,
    const f16* __restrict__ ewH, const f16* __restrict__ ewL,
    const int* __restrict__ rowList, const int* __restrict__ cnt,
    const int* __restrict__ sched, const int* __restrict__ nItems,
    float* __restrict__ part0, float* __restrict__ partRest) {
  __shared__ int rIdx[TR_E];
  const int b = blockIdx.x;
  const int kz = b % SK_E;
  const int item = b / SK_E;
  if (item >= *nItems) return;  // uniform per block, before any barrier
  const int s = sched[item];
  const int e = s & 255;
  const int tile = s >> 8;
  const int count = cnt[e];

  const int tid = threadIdx.x;
  if (tid < TR_E) {
    const int slot = tile * TR_E + tid;
    rIdx[tid] = (slot < count) ? rowList[e * B_ + slot] : 0;
  }
  __syncthreads();

  const int lane = tid & 63;
  const int w = tid >> 6;
  const int rl = lane & 15;  // A row / B col within 16-tile
  const int kq = lane >> 4;

  const int grow0 = rIdx[w * 32 + rl];
  const int grow1 = rIdx[w * 32 + 16 + rl];
  constexpr int KRANGE = D_ / SK_E;  // 256
  constexpr int NCH = KRANGE / 32;   // 8
  const int k0 = kz * KRANGE;

  const f16* pa0h = featH + (size_t)grow0 * D_ + k0 + kq * 8;
  const f16* pa0l = featL + (size_t)grow0 * D_ + k0 + kq * 8;
  const f16* pa1h = featH + (size_t)grow1 * D_ + k0 + kq * 8;
  const f16* pa1l = featL + (size_t)grow1 * D_ + k0 + kq * 8;
  const size_t eoff = (size_t)e * C_ * D_;
  const f16* pbh[4];
  const f16* pbl[4];
#pragma unroll
  for (int ct = 0; ct < 4; ++ct) {
    const size_t co = eoff + (size_t)(ct * 16 + rl) * D_ + k0 + kq * 8;
    pbh[ct] = ewH + co;
    pbl[ct] = ewL + co;
  }

  f32x4 accH[2][4], accC[2][4];
#pragma unroll
  for (int s2 = 0; s2 < 2; ++s2)
#pragma unroll
    for (int ct = 0; ct < 4; ++ct) {
      accH[s2][ct] = (f32x4){0.f, 0.f, 0.f, 0.f};
      accC[s2][ct] = (f32x4){0.f, 0.f, 0.f, 0.f};
    }

  for (int ch = 0; ch < NCH; ++ch) {
    const int ko = ch * 32;
    const f16x8 a0h = *(const f16x8*)(pa0h + ko);
    const f16x8 a0l = *(const f16x8*)(pa0l + ko);
    const f16x8 a1h = *(const f16x8*)(pa1h + ko);
    const f16x8 a1l = *(const f16x8*)(pa1l + ko);
#pragma unroll
    for (int ct = 0; ct < 4; ++ct) {
      const f16x8 bh = *(const f16x8*)(pbh[ct] + ko);
      const f16x8 bl = *(const f16x8*)(pbl[ct] + ko);
      accH[0][ct] = MFMA16(a0h, bh, accH[0][ct]);
      accC[0][ct] = MFMA16(a0h, bl, accC[0][ct]);
      accC[0][ct] = MFMA16(a0l, bh, accC[0][ct]);
      accH[1][ct] = MFMA16(a1h, bh, accH[1][ct]);
      accC[1][ct] = MFMA16(a1h, bl, accC[1][ct]);
      accC[1][ct] = MFMA16(a1l, bh, accC[1][ct]);
    }
  }

  float* pk = kz ? (partRest + (size_t)(kz - 1) * B_ * C_) : part0;
#pragma unroll
  for (int s2 = 0; s2 < 2; ++s2)
#pragma unroll
    for (int reg = 0; reg < 4; ++reg) {
      const int rloc = w * 32 + s2 * 16 + kq * 4 + reg;
      const int slot = tile * TR_E + rloc;
      if (slot < count) {
        const int g = rIdx[rloc];
#pragma unroll
        for (int ct = 0; ct < 4; ++ct)
          pk[(size_t)g * C_ + ct * 16 + rl] =
              accH[s2][ct][reg] + accC[s2][ct][reg] * ILSC;
      }
    }
}

// ---- wave-per-row: reduce y partials (fixed order), bias, softmax, argmax ----
template <int SK>
__global__ __launch_bounds__(256) void finish_rows(
    const float* __restrict__ ypart0, const float* __restrict__ ypartRest,
    const float* __restrict__ eb, const int* __restrict__ eidArr,
    float* __restrict__ out2, float* __restrict__ out3) {
  const int lane = threadIdx.x & 63;
  const int row = (blockIdx.x * 256 + threadIdx.x) >> 6;
  const int eid = eidArr[row];

  float v = eb[eid * C_ + lane];
  v += ypart0[(size_t)row * C_ + lane];
#pragma unroll
  for (int kz = 1; kz < SK; ++kz)
    v += ypartRest[((size_t)(kz - 1) * B_ + row) * C_ + lane];

  float m = v;
#pragma unroll
  for (int off = 32; off; off >>= 1) m = fmaxf(m, __shfl_xor(m, off, 64));
  const float p = __expf(v - m);
  float s = p;
#pragma unroll
  for (int off = 32; off; off >>= 1) s += __shfl_xor(s, off, 64);
  out2[(size_t)row * C_ + lane] = p / s;  // ypart0 aliases out2; read done

  float av = v;
  int ai = lane;
#pragma unroll
  for (int off = 32; off; off >>= 1) {
    const float ov = __shfl_xor(av, off, 64);
    const int oi = __shfl_xor(ai, off, 64);
    if (ov > av || (ov == av && oi < ai)) { av = ov; ai = oi; }
  }
  if (lane == 0) out3[row] = (float)(ai + (eid << 6));
}

extern "C" void kernel_launch(void* const* d_in, const int* in_sizes, int n_in,
                              void* d_out, int out_size, void* d_ws,
                              size_t ws_size, hipStream_t stream) {
  const float* feat = (const float*)d_in[0];  // [B, D]
  const float* cw = (const float*)d_in[1];    // [E, D]
  const float* cb = (const float*)d_in[2];    // [E]
  const float* ew = (const float*)d_in[3];    // [E, C, D]
  const float* eb = (const float*)d_in[4];    // [E, C]

  float* out0 = (float*)d_out;           // coarse_output [B, E]
  float* out1 = out0 + (size_t)B_ * E_;  // expert_id [B] (as float)
  float* out2 = out1 + B_;               // local_preds [B, C]
  float* out3 = out2 + (size_t)B_ * C_;  // global_preds [B]

  // ws (~173 MB; harness provides 512 MiB per observed poison fill):
  char* p = (char*)d_ws;
  f16* featH = (f16*)p;      p += (size_t)B_ * D_ * 2;            // 64 MB
  f16* featL = (f16*)p;      p += (size_t)B_ * D_ * 2;            // 64 MB
  f16* ewH = (f16*)p;        p += (size_t)E_ * C_ * D_ * 2;       // 4 MB
  f16* ewL = (f16*)p;        p += (size_t)E_ * C_ * D_ * 2;       // 4 MB
  f16* cwH = (f16*)p;        p += (size_t)E_ * D_ * 2;            // 64 KB
  f16* cwL = (f16*)p;        p += (size_t)E_ * D_ * 2;            // 64 KB
  float* ypartRest = (float*)p; p += (size_t)(SK_E - 1) * B_ * C_ * 4;  // 29.4 MB
  int* rowList = (int*)p;    p += (size_t)E_ * B_ * 4;            // 1 MB
  int* cnt = (int*)p;        p += 64 * 4;
  int* eidArr = (int*)p;     p += (size_t)B_ * 4;
  int* sched = (int*)p;      p += 512 * 4;
  int* nItems = (int*)p;

  hipMemsetAsync(cnt, 0, E_ * sizeof(int), stream);

  // 1) weights -> f16 hi/lo (8.5 MB, ~3 us)
  convert_w<<<16 + 1024, 256, 0, stream>>>(cw, ew, cwH, cwL, ewH, ewL);
  // 2) fused convert + coarse MFMA + argmax + routing (268 MB streamed)
  coarse_fused<<<B_ / 64, 512, 0, stream>>>(feat, cwH, cwL, cb, featH, featL,
                                            out0, out1, eidArr, cnt, rowList);
  // 3) dense worker list, then MFMA expert GEMM (<=144 items * SK 8)
  make_schedule<<<1, 64, 0, stream>>>(cnt, sched, nItems);
  expert_gemm<<<MAXITEMS * SK_E, 256, 0, stream>>>(
      featH, featL, ewH, ewL, rowList, cnt, sched, nItems, out2, ypartRest);
  // 4) softmax + argmax + class-range start
  finish_rows<SK_E><<<(B_ * 64) / 256, 256, 0, stream>>>(out2, ypartRest, eb,
                                                         eidArr, out2, out3);
}

// Round 4
// 283.194 us; speedup vs baseline: 1.2273x; 1.2273x over previous
//
#include <hip/hip_runtime.h>
#include <cstdint>

// MoE: B=16384 rows, D=2048 feat, E=16 experts, C=64 classes/expert.
// R7: R6's coarse_fused was latency-bound (256 blocks = 1/CU, occ 19%,
// 2.0 TB/s) and wrote 128MB of featH/L. Fix: (1) drop featH/L -- expert GEMM
// reads feat f32 directly (same bytes as f16 h+l, L3-warm from coarse) and
// converts on the fly (identical math to R6); (2) coarse re-gridded to
// 1024 blocks x 512 thr (16 rows/block, K split 8 ways across waves, LDS
// reduce, A+B prefetch, zero K-loop stores) -> memory-bound ~134MB read;
// (3) routing compaction moved to tiny route_build (R3's proven pattern);
// (4) expert GEMM gets explicit next-chunk A prefetch.
// f16x3 scheme (R6-proven): a = hi + lo*2^-11, lo prescaled by 2048;
// accH = hi*hi, accC = hi*lo' + lo'*hi; y = accH + accC/2048.
// Fragment convention (R6-validated): A/B frag = 8 contiguous k at row/col
// (lane&15), k-base (lane>>4)*8; D element = (row = (lane>>4)*4+reg, col =
// lane&15) with row = feat-row, col = weight-col.
typedef _Float16 f16;
typedef f16 f16x8 __attribute__((ext_vector_type(8)));
typedef float f32x4 __attribute__((ext_vector_type(4)));
#define MFMA16(a, b, c) __builtin_amdgcn_mfma_f32_16x16x32_f16((a), (b), (c), 0, 0, 0)

static constexpr int B_ = 16384;
static constexpr int D_ = 2048;
static constexpr int E_ = 16;
static constexpr int C_ = 64;
static constexpr float LSC = 2048.0f;   // lo-term scale (2^11)
static constexpr float ILSC = 1.0f / 2048.0f;
static constexpr int TR_E = 128;        // expert tile rows
static constexpr int SK_E = 8;          // expert split-K
static constexpr int MAXITEMS = (B_ / TR_E) + E_;  // 144 worst case

// f32 -> (hi f16, lo f16 prescaled by 2048). Bitwise identical to R6's math.
__device__ __forceinline__ void cvt_hl(const float4 x, const float4 y,
                                       f16x8& h, f16x8& l) {
  const float av[8] = {x.x, x.y, x.z, x.w, y.x, y.y, y.z, y.w};
#pragma unroll
  for (int j = 0; j < 8; ++j) {
    const f16 hh = (f16)av[j];
    h[j] = hh;
    l[j] = (f16)((av[j] - (float)hh) * LSC);
  }
}

// ---- one-shot weight conversion (cw 128KB + ew 8MB of f16 out, ~4us) ----
__global__ __launch_bounds__(256) void convert_w(
    const float* __restrict__ cw, const float* __restrict__ ew,
    f16* __restrict__ cwH, f16* __restrict__ cwL,
    f16* __restrict__ ewH, f16* __restrict__ ewL) {
  const int g = blockIdx.x;
  const int tid = threadIdx.x;
  const float* src;
  f16 *dh, *dl;
  size_t off;
  if (g < 16) {  // cw: 16*2048 elems
    off = ((size_t)g * 256 + tid) * 8;
    src = cw; dh = cwH; dl = cwL;
  } else {       // ew: 16*64*2048 elems
    off = ((size_t)(g - 16) * 256 + tid) * 8;
    src = ew; dh = ewH; dl = ewL;
  }
  const float4 v0 = *(const float4*)(src + off);
  const float4 v1 = *(const float4*)(src + off + 4);
  f16x8 h8, l8;
  cvt_hl(v0, v1, h8, l8);
  *(f16x8*)(dh + off) = h8;
  *(f16x8*)(dl + off) = l8;
}

// ---- coarse: f32 feat read ONCE, f16x3 MFMA, fused bias+argmax ----
// 1024 blocks x 512 thr (8 waves). Block owns 16 rows; wave w owns K-range
// [w*256, (w+1)*256) as 8 chunks of 32. No K-loop stores; A+B prefetched one
// chunk ahead. 8 partial C tiles reduced through 8KB LDS; epilogue argmax.
__global__ __launch_bounds__(512) void coarse_fused(
    const float* __restrict__ feat, const f16* __restrict__ cwH,
    const f16* __restrict__ cwL, const float* __restrict__ cb,
    float* __restrict__ out0, float* __restrict__ out1,
    int* __restrict__ eidArr) {
  __shared__ float red[8 * 256];  // [wave][localrow*16 + e]
  const int tid = threadIdx.x;
  const int w = tid >> 6;
  const int lane = tid & 63;
  const int rl = lane & 15;   // feat row within block / expert col
  const int kq = lane >> 4;   // k-quad
  const int row = blockIdx.x * 16 + rl;
  const int k0 = w * (D_ / 8);

  const float* fr = feat + (size_t)row * D_ + k0 + kq * 8;
  const f16* bhp = cwH + (size_t)rl * D_ + k0 + kq * 8;
  const f16* blp = cwL + (size_t)rl * D_ + k0 + kq * 8;

  f32x4 aH = {0.f, 0.f, 0.f, 0.f};
  f32x4 aC = {0.f, 0.f, 0.f, 0.f};

  // prefetch chunk 0
  float4 v0 = *(const float4*)(fr);
  float4 v1 = *(const float4*)(fr + 4);
  f16x8 bhn = *(const f16x8*)(bhp);
  f16x8 bln = *(const f16x8*)(blp);
#pragma unroll
  for (int ch = 0; ch < 8; ++ch) {
    const float4 c0 = v0, c1 = v1;
    const f16x8 bh = bhn, bl = bln;
    if (ch + 1 < 8) {  // issue next chunk's loads early
      const int ko = (ch + 1) * 32;
      v0 = *(const float4*)(fr + ko);
      v1 = *(const float4*)(fr + ko + 4);
      bhn = *(const f16x8*)(bhp + ko);
      bln = *(const f16x8*)(blp + ko);
    }
    f16x8 h8, l8;
    cvt_hl(c0, c1, h8, l8);
    aH = MFMA16(h8, bh, aH);
    aC = MFMA16(h8, bl, aC);
    aC = MFMA16(l8, bh, aC);
  }
#pragma unroll
  for (int reg = 0; reg < 4; ++reg)
    red[w * 256 + (kq * 4 + reg) * 16 + rl] = aH[reg] + aC[reg] * ILSC;
  __syncthreads();

  if (tid < 256) {
    const int e = tid & 15;
    const int lrow = tid >> 4;
    float val = cb[e];
#pragma unroll
    for (int ww = 0; ww < 8; ++ww) val += red[ww * 256 + tid];
    const int grow = blockIdx.x * 16 + lrow;
    out0[(size_t)grow * E_ + e] = val;
    // argmax over 16 experts (16-lane group), first-occurrence tie-break
    float av2 = val;
    int ai = e;
#pragma unroll
    for (int off = 8; off; off >>= 1) {
      const float ov = __shfl_xor(av2, off, 16);
      const int oi = __shfl_xor(ai, off, 16);
      if (ov > av2 || (ov == av2 && oi < ai)) { av2 = ov; ai = oi; }
    }
    if (e == 0) {
      out1[grow] = (float)ai;
      eidArr[grow] = ai;
    }
  }
}

// ---- routing compaction (R3-proven block-aggregated atomic pattern) ----
__global__ __launch_bounds__(256) void route_build(
    const int* __restrict__ eidArr, int* __restrict__ cnt,
    int* __restrict__ rowList) {
  __shared__ int lcnt[E_];
  __shared__ int lbase[E_];
  const int tid = threadIdx.x;
  if (tid < E_) lcnt[tid] = 0;
  __syncthreads();
  const int row = blockIdx.x * 256 + tid;
  const int best = eidArr[row];
  const int lpos = atomicAdd(&lcnt[best], 1);
  __syncthreads();
  if (tid < E_) lbase[tid] = atomicAdd(&cnt[tid], lcnt[tid]);
  __syncthreads();
  rowList[best * B_ + lbase[best] + lpos] = row;
}

// ---- dense (e, tile) worker list for the expert GEMM ----
__global__ void make_schedule(const int* __restrict__ cnt,
                              int* __restrict__ sched,
                              int* __restrict__ nItems) {
  __shared__ int tiles[E_];
  __shared__ int offs[E_];
  const int t = threadIdx.x;
  if (t < E_) tiles[t] = (cnt[t] + TR_E - 1) / TR_E;
  __syncthreads();
  if (t == 0) {
    int acc = 0;
    for (int e = 0; e < E_; ++e) { offs[e] = acc; acc += tiles[e]; }
    *nItems = acc;
  }
  __syncthreads();
  if (t < E_) {
    const int o = offs[t], n = tiles[t];
    for (int k = 0; k < n; ++k) sched[o + k] = t | (k << 8);
  }
}

// ---- expert GEMM: f16x3 MFMA; A from f32 feat (L3-warm) converted on the
// fly + prefetched one chunk ahead; B direct from L2-hot ewH/ewL ----
__global__ __launch_bounds__(256) void expert_gemm(
    const float* __restrict__ feat,
    const f16* __restrict__ ewH, const f16* __restrict__ ewL,
    const int* __restrict__ rowList, const int* __restrict__ cnt,
    const int* __restrict__ sched, const int* __restrict__ nItems,
    float* __restrict__ part0, float* __restrict__ partRest) {
  __shared__ int rIdx[TR_E];
  const int b = blockIdx.x;
  const int kz = b % SK_E;
  const int item = b / SK_E;
  if (item >= *nItems) return;  // uniform per block, before any barrier
  const int s = sched[item];
  const int e = s & 255;
  const int tile = s >> 8;
  const int count = cnt[e];

  const int tid = threadIdx.x;
  if (tid < TR_E) {
    const int slot = tile * TR_E + tid;
    rIdx[tid] = (slot < count) ? rowList[e * B_ + slot] : 0;
  }
  __syncthreads();

  const int lane = tid & 63;
  const int w = tid >> 6;
  const int rl = lane & 15;
  const int kq = lane >> 4;

  const int grow0 = rIdx[w * 32 + rl];
  const int grow1 = rIdx[w * 32 + 16 + rl];
  constexpr int KRANGE = D_ / SK_E;  // 256
  constexpr int NCH = KRANGE / 32;   // 8
  const int k0 = kz * KRANGE;

  const float* pa0 = feat + (size_t)grow0 * D_ + k0 + kq * 8;
  const float* pa1 = feat + (size_t)grow1 * D_ + k0 + kq * 8;
  const size_t eoff = (size_t)e * C_ * D_;
  const f16* pbh[4];
  const f16* pbl[4];
#pragma unroll
  for (int ct = 0; ct < 4; ++ct) {
    const size_t co = eoff + (size_t)(ct * 16 + rl) * D_ + k0 + kq * 8;
    pbh[ct] = ewH + co;
    pbl[ct] = ewL + co;
  }

  f32x4 accH[2][4], accC[2][4];
#pragma unroll
  for (int s2 = 0; s2 < 2; ++s2)
#pragma unroll
    for (int ct = 0; ct < 4; ++ct) {
      accH[s2][ct] = (f32x4){0.f, 0.f, 0.f, 0.f};
      accC[s2][ct] = (f32x4){0.f, 0.f, 0.f, 0.f};
    }

  // prefetch chunk 0 A (f32)
  float4 n0a = *(const float4*)(pa0);
  float4 n0b = *(const float4*)(pa0 + 4);
  float4 n1a = *(const float4*)(pa1);
  float4 n1b = *(const float4*)(pa1 + 4);
#pragma unroll
  for (int ch = 0; ch < NCH; ++ch) {
    const float4 c0a = n0a, c0b = n0b, c1a = n1a, c1b = n1b;
    if (ch + 1 < NCH) {
      const int kn = (ch + 1) * 32;
      n0a = *(const float4*)(pa0 + kn);
      n0b = *(const float4*)(pa0 + kn + 4);
      n1a = *(const float4*)(pa1 + kn);
      n1b = *(const float4*)(pa1 + kn + 4);
    }
    f16x8 a0h, a0l, a1h, a1l;
    cvt_hl(c0a, c0b, a0h, a0l);
    cvt_hl(c1a, c1b, a1h, a1l);
    const int ko = ch * 32;
#pragma unroll
    for (int ct = 0; ct < 4; ++ct) {
      const f16x8 bh = *(const f16x8*)(pbh[ct] + ko);
      const f16x8 bl = *(const f16x8*)(pbl[ct] + ko);
      accH[0][ct] = MFMA16(a0h, bh, accH[0][ct]);
      accC[0][ct] = MFMA16(a0h, bl, accC[0][ct]);
      accC[0][ct] = MFMA16(a0l, bh, accC[0][ct]);
      accH[1][ct] = MFMA16(a1h, bh, accH[1][ct]);
      accC[1][ct] = MFMA16(a1h, bl, accC[1][ct]);
      accC[1][ct] = MFMA16(a1l, bh, accC[1][ct]);
    }
  }

  float* pk = kz ? (partRest + (size_t)(kz - 1) * B_ * C_) : part0;
#pragma unroll
  for (int s2 = 0; s2 < 2; ++s2)
#pragma unroll
    for (int reg = 0; reg < 4; ++reg) {
      const int rloc = w * 32 + s2 * 16 + kq * 4 + reg;
      const int slot = tile * TR_E + rloc;
      if (slot < count) {
        const int g = rIdx[rloc];
#pragma unroll
        for (int ct = 0; ct < 4; ++ct)
          pk[(size_t)g * C_ + ct * 16 + rl] =
              accH[s2][ct][reg] + accC[s2][ct][reg] * ILSC;
      }
    }
}

// ---- wave-per-row: reduce y partials (fixed order), bias, softmax, argmax ----
template <int SK>
__global__ __launch_bounds__(256) void finish_rows(
    const float* __restrict__ ypart0, const float* __restrict__ ypartRest,
    const float* __restrict__ eb, const int* __restrict__ eidArr,
    float* __restrict__ out2, float* __restrict__ out3) {
  const int lane = threadIdx.x & 63;
  const int row = (blockIdx.x * 256 + threadIdx.x) >> 6;
  const int eid = eidArr[row];

  float v = eb[eid * C_ + lane];
  v += ypart0[(size_t)row * C_ + lane];
#pragma unroll
  for (int kz = 1; kz < SK; ++kz)
    v += ypartRest[((size_t)(kz - 1) * B_ + row) * C_ + lane];

  float m = v;
#pragma unroll
  for (int off = 32; off; off >>= 1) m = fmaxf(m, __shfl_xor(m, off, 64));
  const float p = __expf(v - m);
  float s = p;
#pragma unroll
  for (int off = 32; off; off >>= 1) s += __shfl_xor(s, off, 64);
  out2[(size_t)row * C_ + lane] = p / s;  // ypart0 aliases out2; read done

  float av = v;
  int ai = lane;
#pragma unroll
  for (int off = 32; off; off >>= 1) {
    const float ov = __shfl_xor(av, off, 64);
    const int oi = __shfl_xor(ai, off, 64);
    if (ov > av || (ov == av && oi < ai)) { av = ov; ai = oi; }
  }
  if (lane == 0) out3[row] = (float)(ai + (eid << 6));
}

extern "C" void kernel_launch(void* const* d_in, const int* in_sizes, int n_in,
                              void* d_out, int out_size, void* d_ws,
                              size_t ws_size, hipStream_t stream) {
  const float* feat = (const float*)d_in[0];  // [B, D]
  const float* cw = (const float*)d_in[1];    // [E, D]
  const float* cb = (const float*)d_in[2];    // [E]
  const float* ew = (const float*)d_in[3];    // [E, C, D]
  const float* eb = (const float*)d_in[4];    // [E, C]

  float* out0 = (float*)d_out;           // coarse_output [B, E]
  float* out1 = out0 + (size_t)B_ * E_;  // expert_id [B] (as float)
  float* out2 = out1 + B_;               // local_preds [B, C]
  float* out3 = out2 + (size_t)B_ * C_;  // global_preds [B]

  // ws (~40 MB): f16 weights + kz>=1 y-partials + routing metadata.
  char* p = (char*)d_ws;
  f16* ewH = (f16*)p;        p += (size_t)E_ * C_ * D_ * 2;       // 4 MB
  f16* ewL = (f16*)p;        p += (size_t)E_ * C_ * D_ * 2;       // 4 MB
  f16* cwH = (f16*)p;        p += (size_t)E_ * D_ * 2;            // 64 KB
  f16* cwL = (f16*)p;        p += (size_t)E_ * D_ * 2;            // 64 KB
  float* ypartRest = (float*)p; p += (size_t)(SK_E - 1) * B_ * C_ * 4;  // 29.4 MB
  int* rowList = (int*)p;    p += (size_t)E_ * B_ * 4;            // 1 MB
  int* cnt = (int*)p;        p += 64 * 4;
  int* eidArr = (int*)p;     p += (size_t)B_ * 4;
  int* sched = (int*)p;      p += 512 * 4;
  int* nItems = (int*)p;

  hipMemsetAsync(cnt, 0, E_ * sizeof(int), stream);

  // 1) weights -> f16 hi/lo (8.5 MB out, ~4 us)
  convert_w<<<16 + 1024, 256, 0, stream>>>(cw, ew, cwH, cwL, ewH, ewL);
  // 2) coarse MFMA + argmax (134 MB streamed; 1024 blocks, 32 waves/CU)
  coarse_fused<<<B_ / 16, 512, 0, stream>>>(feat, cwH, cwL, cb, out0, out1,
                                            eidArr);
  // 3) routing compaction + dense worker list
  route_build<<<B_ / 256, 256, 0, stream>>>(eidArr, cnt, rowList);
  make_schedule<<<1, 64, 0, stream>>>(cnt, sched, nItems);
  // 4) expert MFMA GEMM (<=144 items * SK 8 = 1152 blocks)
  expert_gemm<<<MAXITEMS * SK_E, 256, 0, stream>>>(
      feat, ewH, ewL, rowList, cnt, sched, nItems, out2, ypartRest);
  // 5) softmax + argmax + class-range start
  finish_rows<SK_E><<<(B_ * 64) / 256, 256, 0, stream>>>(out2, ypartRest, eb,
                                                         eidArr, out2, out3);
}